// Round 6
// baseline (60.081 us; speedup 1.0000x reference)
//
#include <hip/hip_runtime.h>
#include <math.h>

#define H 64
#define VOCAB 64
#define LSEQ 4096
#define NSLOTS 4
#define NP 3
#define EPS 1e-5f
#define BARRIER_OFF (1u << 20)

typedef unsigned long long ull;

__device__ __forceinline__ float wsum(float x) {
    #pragma unroll
    for (int m = 1; m < 64; m <<= 1) x += __shfl_xor(x, m);
    return x;
}
__device__ __forceinline__ float wmax(float x) {
    #pragma unroll
    for (int m = 1; m < 64; m <<= 1) x = fmaxf(x, __shfl_xor(x, m));
    return x;
}

// ws layout (floats):
//   enc_t  [64][64]        @ 0
//   score  [64]            @ 4096
//   c_t    [3][64v]        @ 4160
//   q_t    [64][64]        @ 4352
//   MT     [3][64v][64d]   @ 8448
//   SvT    [3][64h][64v]   @ 20736
//   owT    [64v][64h]      @ 33024
//   barrier counter        @ byte offset 1 MiB (memset to 0 each launch)

#define PASS(P, MC, MN, VC, VN, CCV, RGV, RBV, LOADNEXT)                       \
{                                                                              \
    if (LOADNEXT) {                                                            \
      const float4* b4 = (const float4*)(MT + ((P) + 1) * 4096 + lane * 64);   \
      _Pragma("unroll") for (int i = 0; i < 16; i++) MN[i] = b4[i];            \
      const float4* c4 = (const float4*)(SvT + ((P) + 1) * 4096 + lane * 64);  \
      _Pragma("unroll") for (int i = 0; i < 16; i++) VN[i] = c4[i];            \
    }                                                                          \
    sls[wid][lane] = s;                                                        \
    const float4* sp = (const float4*)sls[wid];                                \
    float a0 = 0, a1x = 0, a2 = 0, a3 = 0;                                     \
    _Pragma("unroll") for (int i = 0; i < 16; i++) {                           \
        float4 s4v = sp[i];                                                    \
        a0 += s4v.x * MC[i].x; a1x += s4v.y * MC[i].y;                         \
        a2 += s4v.z * MC[i].z; a3 += s4v.w * MC[i].w; }                        \
    float lg = (CCV + ((a0 + a1x) + (a2 + a3))) * 0.125f;                      \
    float w  = cntf * __expf(lg);                                              \
    float denom = wsum(w);                                                     \
    wls[wid][lane] = w;                                                        \
    const float4* wp = (const float4*)wls[wid];                                \
    float b0 = 0, b1 = 0, b2 = 0, b3 = 0;                                      \
    _Pragma("unroll") for (int i = 0; i < 16; i++) {                           \
        float4 w4 = wp[i];                                                     \
        b0 += w4.x * VC[i].x; b1 += w4.y * VC[i].y;                            \
        b2 += w4.z * VC[i].z; b3 += w4.w * VC[i].w; }                          \
    float x = s + ((b0 + b1) + (b2 + b3)) / denom;                             \
    float s1 = x, s2v = x * x;                                                 \
    _Pragma("unroll") for (int m = 1; m < 64; m <<= 1) {                       \
        s1 += __shfl_xor(s1, m); s2v += __shfl_xor(s2v, m); }                  \
    float mu  = s1 * (1.f / 64.f);                                             \
    float var = s2v * (1.f / 64.f) - mu * mu;                                  \
    s = (x - mu) * rsqrtf(var + EPS) * RGV + RBV;                              \
}

__global__ __launch_bounds__(256) void fused(
    const int*   __restrict__ seq,
    const float* __restrict__ embed,
    const float* __restrict__ ff1_w, const float* __restrict__ ff1_b,
    const float* __restrict__ ff2_w, const float* __restrict__ ff2_b,
    const float* __restrict__ enc_g, const float* __restrict__ enc_b,
    const float* __restrict__ g1_w,  const float* __restrict__ g1_b,
    const float* __restrict__ g2_w,  const float* __restrict__ g2_b,
    const float* __restrict__ rq_w,  const float* __restrict__ rq_b,
    const float* __restrict__ rk_w,  const float* __restrict__ rk_b,
    const float* __restrict__ rv_w,  const float* __restrict__ rv_b,
    const float* __restrict__ rn_g,  const float* __restrict__ rn_b,
    const float* __restrict__ rd_q_w, const float* __restrict__ rd_q_b,
    const float* __restrict__ out_w, const float* __restrict__ out_b,
    float* __restrict__ enc_t, float* __restrict__ score_t,
    float* __restrict__ c_t, float* __restrict__ q_t,
    float* __restrict__ MT, float* __restrict__ SvT, float* __restrict__ owT,
    unsigned* __restrict__ barp,
    float* __restrict__ out)
{
    const int bid = blockIdx.x, tid = threadIdx.x;
    const int wid = tid >> 6, lane = tid & 63;

    __shared__ float bld[4][320];
    __shared__ int   whist[4][64];
    __shared__ int   last_sh;
    __shared__ float sls[4][64], wls[4][64], slN[4][64];
    __shared__ float l4[4];
    __shared__ float rbuf[64];

    // ---------- phase A ----------
    // issue seq loads first (HBM latency hides under build compute)
    const int4* s4 = (const int4*)(seq + (size_t)bid * LSEQ);
    int4 t0 = s4[tid];
    int4 t1 = s4[tid + 256];
    int4 t2 = s4[tid + 512];
    int4 t3 = s4[tid + 768];
    if (tid == 255) last_sh = t3.w;
    whist[wid][lane] = 0;

    // d_in (non-ws) preloads — legal before the barrier
    float rg0 = rn_g[lane], rg1 = rn_g[64 + lane], rg2 = rn_g[128 + lane];
    float rb0 = rn_b[lane], rb1 = rn_b[64 + lane], rb2 = rn_b[128 + lane];
    float ob  = out_b[lane];

    // build tasks: 384 wave-tasks (6 segs x 64 tokens), wave-local LDS slab
    for (int t = bid * 4 + wid; t < 6 * 64; t += gridDim.x * 4) {
        const int seg = t >> 6, v = t & 63;
        float* h_s   = bld[wid];
        float* a1p   = bld[wid] + 64;
        float* hid_s = bld[wid] + 192;
        float* sk_s  = bld[wid] + 256;

        h_s[lane] = embed[v * H + lane];
        __builtin_amdgcn_wave_barrier();

        float pA[4] = {0, 0, 0, 0}, pB[4] = {0, 0, 0, 0};
        #pragma unroll
        for (int c4 = 0; c4 < 4; c4++)
            #pragma unroll
            for (int d = 0; d < 16; d++) {
                int dd = c4 * 16 + d;
                float hv = h_s[dd];
                pA[c4] += hv * ff1_w[dd * 128 + lane];
                pB[c4] += hv * ff1_w[dd * 128 + lane + 64];
            }
        a1p[lane]      = fmaxf(ff1_b[lane]      + ((pA[0] + pA[1]) + (pA[2] + pA[3])), 0.f);
        a1p[lane + 64] = fmaxf(ff1_b[lane + 64] + ((pB[0] + pB[1]) + (pB[2] + pB[3])), 0.f);
        __builtin_amdgcn_wave_barrier();

        float pO[4] = {0, 0, 0, 0};
        #pragma unroll
        for (int c4 = 0; c4 < 4; c4++)
            #pragma unroll
            for (int j = 0; j < 32; j++) {
                int jj = c4 * 32 + j;
                pO[c4] += a1p[jj] * ff2_w[jj * H + lane];
            }
        float o = ff2_b[lane] + ((pO[0] + pO[1]) + (pO[2] + pO[3]));

        float x = h_s[lane] + o;
        float s1 = x, s2 = x * x;
        #pragma unroll
        for (int m = 1; m < 64; m <<= 1) { s1 += __shfl_xor(s1, m); s2 += __shfl_xor(s2, m); }
        float mu  = s1 * (1.f / 64.f);
        float var = s2 * (1.f / 64.f) - mu * mu;
        float hid = (x - mu) * rsqrtf(var + EPS) * enc_g[lane] + enc_b[lane];
        hid_s[lane] = hid;
        __builtin_amdgcn_wave_barrier();

        if (seg == 0) {
            enc_t[v * H + lane] = hid;
            float p = 0.f;
            if (lane < 32) {
                float a[2] = {0, 0};
                #pragma unroll
                for (int c2 = 0; c2 < 2; c2++)
                    #pragma unroll
                    for (int d = 0; d < 32; d++) {
                        int dd = c2 * 32 + d;
                        a[c2] += hid_s[dd] * g1_w[dd * 32 + lane];
                    }
                p = fmaxf(g1_b[lane] + a[0] + a[1], 0.f) * g2_w[lane];
            }
            p = wsum(p);
            if (lane == 0) score_t[v] = 1.f / (1.f + expf(-(p + g2_b[0])));
            float qa[4] = {0, 0, 0, 0};
            #pragma unroll
            for (int c4 = 0; c4 < 4; c4++)
                #pragma unroll
                for (int d = 0; d < 16; d++) {
                    int dd = c4 * 16 + d;
                    qa[c4] += hid_s[dd] * rd_q_w[dd * H + lane];
                }
            q_t[v * H + lane] = rd_q_b[lane] + ((qa[0] + qa[1]) + (qa[2] + qa[3]));
        }
        if (seg < 3) {
            const int p = seg;
            float ka[4] = {0, 0, 0, 0};
            #pragma unroll
            for (int c4 = 0; c4 < 4; c4++)
                #pragma unroll
                for (int d = 0; d < 16; d++) {
                    int dd = c4 * 16 + d;
                    ka[c4] += hid_s[dd] * rk_w[(p * H + dd) * H + lane];
                }
            float skv = rk_b[p * H + lane] + ((ka[0] + ka[1]) + (ka[2] + ka[3]));
            sk_s[lane] = skv;
            float cpart = wsum(rq_b[p * H + lane] * skv);
            if (lane == 0) c_t[p * 64 + v] = cpart;
            __builtin_amdgcn_wave_barrier();
            const float4* rw4 = (const float4*)(rq_w + (size_t)(p * 64 + lane) * 64);
            const float4* sk4 = (const float4*)sk_s;
            float ma[4] = {0, 0, 0, 0};
            #pragma unroll
            for (int i = 0; i < 16; i++) {
                float4 w4 = rw4[i];
                float4 s4v = sk4[i];
                ma[0] += w4.x * s4v.x; ma[1] += w4.y * s4v.y;
                ma[2] += w4.z * s4v.z; ma[3] += w4.w * s4v.w;
            }
            MT[p * 4096 + v * 64 + lane] = ((ma[0] + ma[1]) + (ma[2] + ma[3]));
        } else {
            const int p = seg - 3;
            float va[4] = {0, 0, 0, 0};
            #pragma unroll
            for (int c4 = 0; c4 < 4; c4++)
                #pragma unroll
                for (int d = 0; d < 16; d++) {
                    int dd = c4 * 16 + d;
                    va[c4] += hid_s[dd] * rv_w[(p * H + dd) * H + lane];
                }
            float svv = rv_b[p * H + lane] + ((va[0] + va[1]) + (va[2] + va[3]));
            SvT[p * 4096 + lane * 64 + v] = svv;
            if (seg == 3) owT[v * 64 + lane] = out_w[lane * 64 + v];
        }
    }

    // histogram (wave-private banks; seq loads have landed by now)
    {
        int* hw = whist[wid];
        atomicAdd(&hw[t0.x], 1); atomicAdd(&hw[t0.y], 1);
        atomicAdd(&hw[t0.z], 1); atomicAdd(&hw[t0.w], 1);
        atomicAdd(&hw[t1.x], 1); atomicAdd(&hw[t1.y], 1);
        atomicAdd(&hw[t1.z], 1); atomicAdd(&hw[t1.w], 1);
        atomicAdd(&hw[t2.x], 1); atomicAdd(&hw[t2.y], 1);
        atomicAdd(&hw[t2.z], 1); atomicAdd(&hw[t2.w], 1);
        atomicAdd(&hw[t3.x], 1); atomicAdd(&hw[t3.y], 1);
        atomicAdd(&hw[t3.z], 1); atomicAdd(&hw[t3.w], 1);
    }
    __syncthreads();

    // ---------- device-wide spin barrier (release -> arrive -> spin -> acquire) ----------
    if (tid == 0) {
        __threadfence();                       // flush this XCD's L2 (tables -> IC)
        atomicAdd(barp, 1u);
        while (atomicAdd(barp, 0u) < (unsigned)gridDim.x)
            __builtin_amdgcn_s_sleep(2);
    }
    __syncthreads();
    __threadfence();                           // invalidate stale L1/L2 before table reads

    // ---------- phase B ----------
    const int cnt = whist[0][lane] + whist[1][lane] + whist[2][lane] + whist[3][lane];
    const float cntf = (float)cnt;

    float sc = score_t[lane];
    float4 mA[16], mB[16], vA[16], vB[16];
    {   // pass-0 tables in flight during selection
        const float4* p4 = (const float4*)(MT + lane * 64);
        #pragma unroll
        for (int i = 0; i < 16; i++) mA[i] = p4[i];
        const float4* q4 = (const float4*)(SvT + lane * 64);
        #pragma unroll
        for (int i = 0; i < 16; i++) vA[i] = q4[i];
    }
    float cc0 = c_t[lane], cc1 = c_t[64 + lane], cc2 = c_t[128 + lane];

    // selection, redundant per wave: greedy by (score desc, token asc), fill by counts
    int my_tok = 0;
    {
        float key = cnt > 0 ? sc : -1.f;
        int filled = 0;
        bool have = false;
        #pragma unroll 1
        for (int r = 0; r < NSLOTS && filled < NSLOTS; r++) {
            float m = wmax(key);
            ull win = __ballot(key == m);
            int tk = __ffsll(win) - 1;
            int c  = __shfl(cnt, tk);
            if (!have && (unsigned)(wid - filled) < (unsigned)c) { my_tok = tk; have = true; }
            filled += c;
            if (lane == tk) key = -1.f;
        }
    }

    float s = enc_t[my_tok * 64 + lane];
    float q = q_t[last_sh * 64 + lane];

    PASS(0, mA, mB, vA, vB, cc0, rg0, rb0, 1)
    PASS(1, mB, mA, vB, vA, cc1, rg1, rb1, 1)
    PASS(2, mA, mB, vA, vB, cc2, rg2, rb2, 0)

    float lk = wsum(s * q) * 0.125f;
    if (lane == 0) l4[wid] = lk;
    slN[wid][lane] = s;

    float4 ow[16];
    if (wid == 0) {
        const float4* b4 = (const float4*)(owT + lane * 64);
        #pragma unroll
        for (int i = 0; i < 16; i++) ow[i] = b4[i];
    }
    __syncthreads();

    if (wid == 0) {
        float e0 = __expf(l4[0]), e1 = __expf(l4[1]);
        float e2 = __expf(l4[2]), e3 = __expf(l4[3]);
        float dn = e0 + e1 + e2 + e3;
        float r = (e0 * slN[0][lane] + e1 * slN[1][lane]
                 + e2 * slN[2][lane] + e3 * slN[3][lane]) / dn;
        rbuf[lane] = r;
        __builtin_amdgcn_wave_barrier();
        const float4* rp = (const float4*)rbuf;
        float o0 = ob, o1 = 0.f, o2 = 0.f, o3 = 0.f;
        #pragma unroll
        for (int i = 0; i < 16; i++) {
            float4 rv = rp[i];
            o0 += rv.x * ow[i].x; o1 += rv.y * ow[i].y;
            o2 += rv.z * ow[i].z; o3 += rv.w * ow[i].w;
        }
        out[(size_t)bid * VOCAB + lane] = ((o0 + o1) + (o2 + o3));
    }
}

extern "C" void kernel_launch(void* const* d_in, const int* in_sizes, int n_in,
                              void* d_out, int out_size, void* d_ws, size_t ws_size,
                              hipStream_t stream) {
    const int*   seq    = (const int*)  d_in[0];
    const float* embed  = (const float*)d_in[1];
    const float* ff1_w  = (const float*)d_in[2];
    const float* ff1_b  = (const float*)d_in[3];
    const float* ff2_w  = (const float*)d_in[4];
    const float* ff2_b  = (const float*)d_in[5];
    const float* enc_g  = (const float*)d_in[6];
    const float* enc_b  = (const float*)d_in[7];
    const float* g1_w   = (const float*)d_in[8];
    const float* g1_b   = (const float*)d_in[9];
    const float* g2_w   = (const float*)d_in[10];
    const float* g2_b   = (const float*)d_in[11];
    const float* rq_w   = (const float*)d_in[12];
    const float* rq_b   = (const float*)d_in[13];
    const float* rk_w   = (const float*)d_in[14];
    const float* rk_b   = (const float*)d_in[15];
    const float* rv_w   = (const float*)d_in[16];
    const float* rv_b   = (const float*)d_in[17];
    const float* rn_g   = (const float*)d_in[18];
    const float* rn_b   = (const float*)d_in[19];
    const float* rd_q_w = (const float*)d_in[20];
    const float* rd_q_b = (const float*)d_in[21];
    const float* out_w  = (const float*)d_in[22];
    const float* out_b  = (const float*)d_in[23];
    float* out = (float*)d_out;

    const int B = in_sizes[0] / LSEQ;

    float* ws      = (float*)d_ws;
    float* enc_t   = ws;                // 4096
    float* score_t = ws + 4096;         // 64
    float* c_t     = ws + 4160;         // 192
    float* q_t     = ws + 4352;         // 4096
    float* MT      = ws + 8448;         // 12288
    float* SvT     = ws + 20736;        // 12288
    float* owT     = ws + 33024;        // 4096
    unsigned* barp = (unsigned*)((char*)d_ws + BARRIER_OFF);

    hipMemsetAsync(barp, 0, 64, stream);

    fused<<<B, 256, 0, stream>>>(
        seq, embed, ff1_w, ff1_b, ff2_w, ff2_b, enc_g, enc_b,
        g1_w, g1_b, g2_w, g2_b,
        rq_w, rq_b, rk_w, rk_b, rv_w, rv_b, rn_g, rn_b,
        rd_q_w, rd_q_b, out_w, out_b,
        enc_t, score_t, c_t, q_t, MT, SvT, owT, barp, out);
}

// Round 7
// 22.761 us; speedup vs baseline: 2.6397x; 2.6397x over previous
//
#include <hip/hip_runtime.h>
#include <math.h>

#define H 64
#define VOCAB 64
#define LSEQ 4096
#define NSLOTS 4
#define NP 3
#define EPS 1e-5f

typedef unsigned long long ull;

__device__ __forceinline__ float wsum(float x) {
    #pragma unroll
    for (int m = 1; m < 64; m <<= 1) x += __shfl_xor(x, m);
    return x;
}
__device__ __forceinline__ float wmax(float x) {
    #pragma unroll
    for (int m = 1; m < 64; m <<= 1) x = fmaxf(x, __shfl_xor(x, m));
    return x;
}

// ws layout (floats):
//   enc_t  [64][64]        @ 0
//   score  [64]            @ 4096
//   c_t    [3][64v]        @ 4160
//   q_t    [64][64]        @ 4352
//   MT     [3][64v][64d]   @ 8448
//   SvT    [3][64h][64v]   @ 20736
//   owT    [64v][64h]      @ 33024

// ---- kernel 1: ALL tables in one launch. 384 blocks = 6 segs x 64 tokens. ----
__global__ __launch_bounds__(64) void build_all(
    const float* __restrict__ embed,
    const float* __restrict__ ff1_w, const float* __restrict__ ff1_b,
    const float* __restrict__ ff2_w, const float* __restrict__ ff2_b,
    const float* __restrict__ enc_g, const float* __restrict__ enc_b,
    const float* __restrict__ g1_w,  const float* __restrict__ g1_b,
    const float* __restrict__ g2_w,  const float* __restrict__ g2_b,
    const float* __restrict__ rq_w,  const float* __restrict__ rq_b,
    const float* __restrict__ rk_w,  const float* __restrict__ rk_b,
    const float* __restrict__ rv_w,  const float* __restrict__ rv_b,
    const float* __restrict__ rd_q_w, const float* __restrict__ rd_q_b,
    const float* __restrict__ out_w,
    float* __restrict__ enc_t, float* __restrict__ score_t,
    float* __restrict__ c_t, float* __restrict__ q_t,
    float* __restrict__ MT, float* __restrict__ SvT, float* __restrict__ owT)
{
    const int seg  = blockIdx.x >> 6;
    const int v    = blockIdx.x & 63;
    const int lane = threadIdx.x;

    __shared__ float h_s[H];
    __shared__ float a1[2 * H];
    __shared__ float hid_s[H];
    __shared__ float sk_s[H];

    h_s[lane] = embed[v * H + lane];
    __syncthreads();

    float pA[4] = {0, 0, 0, 0}, pB[4] = {0, 0, 0, 0};
    #pragma unroll
    for (int c4 = 0; c4 < 4; c4++)
        #pragma unroll
        for (int d = 0; d < 16; d++) {
            int dd = c4 * 16 + d;
            float hv = h_s[dd];
            pA[c4] += hv * ff1_w[dd * 128 + lane];
            pB[c4] += hv * ff1_w[dd * 128 + lane + 64];
        }
    a1[lane]      = fmaxf(ff1_b[lane]      + ((pA[0] + pA[1]) + (pA[2] + pA[3])), 0.f);
    a1[lane + 64] = fmaxf(ff1_b[lane + 64] + ((pB[0] + pB[1]) + (pB[2] + pB[3])), 0.f);
    __syncthreads();

    float pO[4] = {0, 0, 0, 0};
    #pragma unroll
    for (int c4 = 0; c4 < 4; c4++)
        #pragma unroll
        for (int j = 0; j < 32; j++) {
            int jj = c4 * 32 + j;
            pO[c4] += a1[jj] * ff2_w[jj * H + lane];
        }
    float o = ff2_b[lane] + ((pO[0] + pO[1]) + (pO[2] + pO[3]));

    float x = h_s[lane] + o;
    float s1 = x, s2 = x * x;
    #pragma unroll
    for (int m = 1; m < 64; m <<= 1) { s1 += __shfl_xor(s1, m); s2 += __shfl_xor(s2, m); }
    float mu  = s1 * (1.f / 64.f);
    float var = s2 * (1.f / 64.f) - mu * mu;
    float hid = (x - mu) * rsqrtf(var + EPS) * enc_g[lane] + enc_b[lane];
    hid_s[lane] = hid;
    __syncthreads();

    if (seg == 0) {
        enc_t[v * H + lane] = hid;
        float p = 0.f;
        if (lane < 32) {
            float a[2] = {0, 0};
            #pragma unroll
            for (int c2 = 0; c2 < 2; c2++)
                #pragma unroll
                for (int d = 0; d < 32; d++) {
                    int dd = c2 * 32 + d;
                    a[c2] += hid_s[dd] * g1_w[dd * 32 + lane];
                }
            p = fmaxf(g1_b[lane] + a[0] + a[1], 0.f) * g2_w[lane];
        }
        p = wsum(p);
        if (lane == 0) score_t[v] = 1.f / (1.f + expf(-(p + g2_b[0])));
        float qa[4] = {0, 0, 0, 0};
        #pragma unroll
        for (int c4 = 0; c4 < 4; c4++)
            #pragma unroll
            for (int d = 0; d < 16; d++) {
                int dd = c4 * 16 + d;
                qa[c4] += hid_s[dd] * rd_q_w[dd * H + lane];
            }
        q_t[v * H + lane] = rd_q_b[lane] + ((qa[0] + qa[1]) + (qa[2] + qa[3]));
    }

    if (seg < 3) {
        const int p = seg;
        float ka[4] = {0, 0, 0, 0};
        #pragma unroll
        for (int c4 = 0; c4 < 4; c4++)
            #pragma unroll
            for (int d = 0; d < 16; d++) {
                int dd = c4 * 16 + d;
                ka[c4] += hid_s[dd] * rk_w[(p * H + dd) * H + lane];
            }
        float skv = rk_b[p * H + lane] + ((ka[0] + ka[1]) + (ka[2] + ka[3]));
        sk_s[lane] = skv;
        float cpart = wsum(rq_b[p * H + lane] * skv);
        if (lane == 0) c_t[p * 64 + v] = cpart;
        __syncthreads();
        const float4* rw4 = (const float4*)(rq_w + (size_t)(p * 64 + lane) * 64);
        const float4* sk4 = (const float4*)sk_s;
        float ma[4] = {0, 0, 0, 0};
        #pragma unroll
        for (int i = 0; i < 16; i++) {
            float4 w4 = rw4[i];
            float4 s4v = sk4[i];
            ma[0] += w4.x * s4v.x; ma[1] += w4.y * s4v.y;
            ma[2] += w4.z * s4v.z; ma[3] += w4.w * s4v.w;
        }
        MT[p * 4096 + v * 64 + lane] = ((ma[0] + ma[1]) + (ma[2] + ma[3]));
    } else {
        const int p = seg - 3;
        float va[4] = {0, 0, 0, 0};
        #pragma unroll
        for (int c4 = 0; c4 < 4; c4++)
            #pragma unroll
            for (int d = 0; d < 16; d++) {
                int dd = c4 * 16 + d;
                va[c4] += hid_s[dd] * rv_w[(p * H + dd) * H + lane];
            }
        float svv = rv_b[p * H + lane] + ((va[0] + va[1]) + (va[2] + va[3]));
        SvT[p * 4096 + lane * 64 + v] = svv;
        if (seg == 3) owT[v * 64 + lane] = out_w[lane * 64 + v];
    }
}

// one re-encoding pass with the denom folded into LN:
//   y = s*denom + ao_unnorm;  s' = (y-mu_y)*rsqrt(var_y + EPS*denom^2)*g + b
#define PASS(P, MC, MN, CCV, RGV, RBV, LOADNEXT)                               \
{                                                                              \
    float4 vcur[16];                                                           \
    { const float4* b4 = (const float4*)(SvT + (P) * 4096 + lane * 64);        \
      _Pragma("unroll") for (int i = 0; i < 16; i++) vcur[i] = b4[i]; }        \
    if (LOADNEXT) {                                                            \
      const float4* b4 = (const float4*)(MT + ((P) + 1) * 4096 + lane * 64);   \
      _Pragma("unroll") for (int i = 0; i < 16; i++) MN[i] = b4[i]; }          \
    sls[wid][lane] = s;                                                        \
    const float4* sp = (const float4*)sls[wid];                                \
    float a0 = 0, a1x = 0, a2 = 0, a3 = 0;                                     \
    _Pragma("unroll") for (int i = 0; i < 16; i++) {                           \
        float4 s4v = sp[i];                                                    \
        a0 += s4v.x * MC[i].x; a1x += s4v.y * MC[i].y;                         \
        a2 += s4v.z * MC[i].z; a3 += s4v.w * MC[i].w; }                        \
    float lg = (CCV + ((a0 + a1x) + (a2 + a3))) * 0.125f;                      \
    float w  = cntf * __expf(lg);                                              \
    wls[wid][lane] = w;                                                        \
    float denom = wsum(w);                                                     \
    const float4* wp = (const float4*)wls[wid];                                \
    float b0 = 0, b1 = 0, b2 = 0, b3 = 0;                                      \
    _Pragma("unroll") for (int i = 0; i < 16; i++) {                           \
        float4 w4 = wp[i];                                                     \
        b0 += w4.x * vcur[i].x; b1 += w4.y * vcur[i].y;                        \
        b2 += w4.z * vcur[i].z; b3 += w4.w * vcur[i].w; }                      \
    float y = s * denom + ((b0 + b1) + (b2 + b3));                             \
    float s1 = y, s2v = y * y;                                                 \
    _Pragma("unroll") for (int m = 1; m < 64; m <<= 1) {                       \
        s1 += __shfl_xor(s1, m); s2v += __shfl_xor(s2v, m); }                  \
    float muy  = s1 * (1.f / 64.f);                                            \
    float vary = s2v * (1.f / 64.f) - muy * muy;                               \
    s = (y - muy) * rsqrtf(vary + EPS * denom * denom) * RGV + RBV;            \
}

// ---- kernel 2: per-batch; speculative top-token fast path ----
__global__ __launch_bounds__(256) void run_batches(
    const int*   __restrict__ seq,
    const float* __restrict__ score_t, const float* __restrict__ enc_t,
    const float* __restrict__ c_t, const float* __restrict__ q_t,
    const float* __restrict__ MT, const float* __restrict__ SvT,
    const float* __restrict__ owT,
    const float* __restrict__ rn_g, const float* __restrict__ rn_b,
    const float* __restrict__ out_b,
    float* __restrict__ out)
{
    __shared__ int   whist[4][64];
    __shared__ float sls[4][64], wls[4][64], slN[4][64];
    __shared__ float l4[4];
    __shared__ float rbuf[64];

    const int bid = blockIdx.x, tid = threadIdx.x;
    const int wid = tid >> 6, lane = tid & 63;

    // issue seq loads first (longest-latency)
    const int4* s4 = (const int4*)(seq + (size_t)bid * LSEQ);
    int4 t0 = s4[tid];
    int4 t1 = s4[tid + 256];
    int4 t2 = s4[tid + 512];
    int4 t3 = s4[tid + 768];
    const int last = seq[(size_t)bid * LSEQ + LSEQ - 1];   // uniform broadcast load

    whist[wid][lane] = 0;

    // prefetches independent of seq
    float sc  = score_t[lane];
    float cc0 = c_t[lane],      cc1 = c_t[64 + lane],  cc2 = c_t[128 + lane];
    float rg0 = rn_g[lane],     rg1 = rn_g[64 + lane], rg2 = rn_g[128 + lane];
    float rb0 = rn_b[lane],     rb1 = rn_b[64 + lane], rb2 = rn_b[128 + lane];
    float ob  = out_b[lane];

    // speculative winner: argmax score (batch-independent)
    float mxs  = wmax(sc);
    ull   bm   = __ballot(sc == mxs);
    int   t_star = __ffsll(bm) - 1;
    int   nmax   = __popcll(bm);

    float s = enc_t[t_star * 64 + lane];   // speculative slot vector
    float q = q_t[last * 64 + lane];

    float4 mA[16], mB[16], vA[16];
    {
        const float4* p4 = (const float4*)(MT + lane * 64);
        #pragma unroll
        for (int i = 0; i < 16; i++) mA[i] = p4[i];
        const float4* q4 = (const float4*)(SvT + lane * 64);
        #pragma unroll
        for (int i = 0; i < 16; i++) vA[i] = q4[i];
    }

    // wave 0: speculative pass-0 logits inside the seq-flight shadow
    float lg0 = 0.f;
    if (wid == 0) {
        sls[0][lane] = s;
        const float4* sp = (const float4*)sls[0];
        float a0 = 0, a1x = 0, a2 = 0, a3 = 0;
        #pragma unroll
        for (int i = 0; i < 16; i++) {
            float4 s4v = sp[i];
            a0 += s4v.x * mA[i].x; a1x += s4v.y * mA[i].y;
            a2 += s4v.z * mA[i].z; a3 += s4v.w * mA[i].w;
        }
        lg0 = (cc0 + ((a0 + a1x) + (a2 + a3))) * 0.125f;
    }

    // histogram (wave-private banks)
    {
        int* hw = whist[wid];
        atomicAdd(&hw[t0.x], 1); atomicAdd(&hw[t0.y], 1);
        atomicAdd(&hw[t0.z], 1); atomicAdd(&hw[t0.w], 1);
        atomicAdd(&hw[t1.x], 1); atomicAdd(&hw[t1.y], 1);
        atomicAdd(&hw[t1.z], 1); atomicAdd(&hw[t1.w], 1);
        atomicAdd(&hw[t2.x], 1); atomicAdd(&hw[t2.y], 1);
        atomicAdd(&hw[t2.z], 1); atomicAdd(&hw[t2.w], 1);
        atomicAdd(&hw[t3.x], 1); atomicAdd(&hw[t3.y], 1);
        atomicAdd(&hw[t3.z], 1); atomicAdd(&hw[t3.w], 1);
    }
    __syncthreads();

    const int cnt = whist[0][lane] + whist[1][lane] + whist[2][lane] + whist[3][lane];
    const float cntf = (float)cnt;
    const int cnt_ts = __shfl(cnt, t_star);
    const bool spec = (nmax == 1) && (cnt_ts >= NSLOTS);

    if (spec) {
        // all 4 slots == t_star -> read head output == final slot vector; 1 wave suffices
        if (wid != 0) return;

        // pass 0 tail (logits already in lg0; vA preloaded; prefetch MT pass-1)
        {
            const float4* b4 = (const float4*)(MT + 4096 + lane * 64);
            #pragma unroll
            for (int i = 0; i < 16; i++) mB[i] = b4[i];
            float w = cntf * __expf(lg0);
            wls[0][lane] = w;
            float denom = wsum(w);
            const float4* wp = (const float4*)wls[0];
            float b0 = 0, b1 = 0, b2 = 0, b3 = 0;
            #pragma unroll
            for (int i = 0; i < 16; i++) {
                float4 w4 = wp[i];
                b0 += w4.x * vA[i].x; b1 += w4.y * vA[i].y;
                b2 += w4.z * vA[i].z; b3 += w4.w * vA[i].w;
            }
            float y = s * denom + ((b0 + b1) + (b2 + b3));
            float s1 = y, s2v = y * y;
            #pragma unroll
            for (int m = 1; m < 64; m <<= 1) { s1 += __shfl_xor(s1, m); s2v += __shfl_xor(s2v, m); }
            float muy  = s1 * (1.f / 64.f);
            float vary = s2v * (1.f / 64.f) - muy * muy;
            s = (y - muy) * rsqrtf(vary + EPS * denom * denom) * rg0 + rb0;
        }
        PASS(1, mB, mA, cc1, rg1, rb1, 1)
        PASS(2, mA, mB, cc2, rg2, rb2, 0)

        // read = s (identical slots). Output projection.
        float4 ow[16];
        {
            const float4* b4 = (const float4*)(owT + lane * 64);
            #pragma unroll
            for (int i = 0; i < 16; i++) ow[i] = b4[i];
        }
        rbuf[lane] = s;
        __builtin_amdgcn_wave_barrier();
        const float4* rp = (const float4*)rbuf;
        float o0 = ob, o1 = 0.f, o2 = 0.f, o3 = 0.f;
        #pragma unroll
        for (int i = 0; i < 16; i++) {
            float4 rv = rp[i];
            o0 += rv.x * ow[i].x; o1 += rv.y * ow[i].y;
            o2 += rv.z * ow[i].z; o3 += rv.w * ow[i].w;
        }
        out[(size_t)bid * VOCAB + lane] = ((o0 + o1) + (o2 + o3));
        return;
    }

    // ---- general fallback (rare): exact greedy selection + 4-wave pipeline ----
    int my_tok = 0;
    {
        float key = cnt > 0 ? sc : -1.f;
        int filled = 0;
        bool have = false;
        #pragma unroll 1
        for (int r = 0; r < NSLOTS && filled < NSLOTS; r++) {
            float m2 = wmax(key);
            ull win = __ballot(key == m2);
            int tk = __ffsll(win) - 1;
            int c  = __shfl(cnt, tk);
            if (!have && (unsigned)(wid - filled) < (unsigned)c) { my_tok = tk; have = true; }
            filled += c;
            if (lane == tk) key = -1.f;
        }
    }

    s = enc_t[my_tok * 64 + lane];

    PASS(0, mA, mB, cc0, rg0, rb0, 1)
    PASS(1, mB, mA, cc1, rg1, rb1, 1)
    PASS(2, mA, mB, cc2, rg2, rb2, 0)

    float lk = wsum(s * q) * 0.125f;
    if (lane == 0) l4[wid] = lk;
    slN[wid][lane] = s;

    float4 ow[16];
    if (wid == 0) {
        const float4* b4 = (const float4*)(owT + lane * 64);
        #pragma unroll
        for (int i = 0; i < 16; i++) ow[i] = b4[i];
    }
    __syncthreads();

    if (wid == 0) {
        float e0 = __expf(l4[0]), e1 = __expf(l4[1]);
        float e2 = __expf(l4[2]), e3 = __expf(l4[3]);
        float dn = e0 + e1 + e2 + e3;
        float r = (e0 * slN[0][lane] + e1 * slN[1][lane]
                 + e2 * slN[2][lane] + e3 * slN[3][lane]) / dn;
        rbuf[lane] = r;
        __builtin_amdgcn_wave_barrier();
        const float4* rp = (const float4*)rbuf;
        float o0 = ob, o1 = 0.f, o2 = 0.f, o3 = 0.f;
        #pragma unroll
        for (int i = 0; i < 16; i++) {
            float4 rv = rp[i];
            o0 += rv.x * ow[i].x; o1 += rv.y * ow[i].y;
            o2 += rv.z * ow[i].z; o3 += rv.w * ow[i].w;
        }
        out[(size_t)bid * VOCAB + lane] = ((o0 + o1) + (o2 + o3));
    }
}

extern "C" void kernel_launch(void* const* d_in, const int* in_sizes, int n_in,
                              void* d_out, int out_size, void* d_ws, size_t ws_size,
                              hipStream_t stream) {
    const int*   seq    = (const int*)  d_in[0];
    const float* embed  = (const float*)d_in[1];
    const float* ff1_w  = (const float*)d_in[2];
    const float* ff1_b  = (const float*)d_in[3];
    const float* ff2_w  = (const float*)d_in[4];
    const float* ff2_b  = (const float*)d_in[5];
    const float* enc_g  = (const float*)d_in[6];
    const float* enc_b  = (const float*)d_in[7];
    const float* g1_w   = (const float*)d_in[8];
    const float* g1_b   = (const float*)d_in[9];
    const float* g2_w   = (const float*)d_in[10];
    const float* g2_b   = (const float*)d_in[11];
    const float* rq_w   = (const float*)d_in[12];
    const float* rq_b   = (const float*)d_in[13];
    const float* rk_w   = (const float*)d_in[14];
    const float* rk_b   = (const float*)d_in[15];
    const float* rv_w   = (const float*)d_in[16];
    const float* rv_b   = (const float*)d_in[17];
    const float* rn_g   = (const float*)d_in[18];
    const float* rn_b   = (const float*)d_in[19];
    const float* rd_q_w = (const float*)d_in[20];
    const float* rd_q_b = (const float*)d_in[21];
    const float* out_w  = (const float*)d_in[22];
    const float* out_b  = (const float*)d_in[23];
    float* out = (float*)d_out;

    const int B = in_sizes[0] / LSEQ;

    float* ws      = (float*)d_ws;
    float* enc_t   = ws;                // 4096
    float* score_t = ws + 4096;         // 64
    float* c_t     = ws + 4160;         // 192
    float* q_t     = ws + 4352;         // 4096
    float* MT      = ws + 8448;         // 12288
    float* SvT     = ws + 20736;        // 12288
    float* owT     = ws + 33024;        // 4096

    build_all<<<384, 64, 0, stream>>>(
        embed, ff1_w, ff1_b, ff2_w, ff2_b, enc_g, enc_b,
        g1_w, g1_b, g2_w, g2_b,
        rq_w, rq_b, rk_w, rk_b, rv_w, rv_b,
        rd_q_w, rd_q_b, out_w,
        enc_t, score_t, c_t, q_t, MT, SvT, owT);

    run_batches<<<B, 256, 0, stream>>>(
        seq, score_t, enc_t, c_t, q_t, MT, SvT, owT,
        rn_g, rn_b, out_b, out);
}